// Round 1
// baseline (20984.402 us; speedup 1.0000x reference)
//
#include <hip/hip_runtime.h>

#define TT 256
#define BB 256
#define NINP 256
#define NHID 256
#define ROWS 16
#define NGROUP 16
#define NTHREADS 512

typedef __attribute__((ext_vector_type(8))) __bf16 bf16x8;
typedef __attribute__((ext_vector_type(4))) float f32x4;

__device__ __forceinline__ float fsig(float x) { return 1.0f / (1.0f + __expf(-x)); }
__device__ __forceinline__ float ftanh(float x) {
  float e = __expf(-2.0f * fabsf(x));
  float r = (1.0f - e) / (1.0f + e);
  return copysignf(r, x);
}

template <int ACT>
__device__ __forceinline__ float actf(float x) {
  if (ACT == 0) return fsig(x);
  if (ACT == 1) return fmaxf(x, 0.0f);
  if (ACT == 2) return ftanh(x);
  return x;  // identity
}

// LDS addressing with XOR swizzle: element (row,col) of a [16][stride] bf16 tile
// lives at byte row*stride*2 + ((col*2) ^ ((row&7)<<4)).  16-row stride-1KB/1.5KB
// A-fragment reads would otherwise be same-bank for all 16 rows.
__device__ __forceinline__ int lds_byte(int stride, int row, int col) {
  return row * stride * 2 + ((col * 2) ^ ((row & 7) << 4));
}
__device__ __forceinline__ bf16x8 lds_frag(const __bf16* base, int stride, int row, int col) {
  return *(const bf16x8*)((const char*)base + lds_byte(stride, row, col));
}
__device__ __forceinline__ void lds_put(__bf16* base, int stride, int row, int col, __bf16 v) {
  *(__bf16*)((char*)base + lds_byte(stride, row, col)) = v;
}

__device__ __forceinline__ f32x4 mfma16(bf16x8 a, bf16x8 b, f32x4 c) {
  return __builtin_amdgcn_mfma_f32_16x16x32_bf16(a, b, c, 0, 0, 0);
}

// Write a state (hi/lo split) into a [16][512] slot: cols 0..255 = hi, 256..511 = lo.
__device__ __forceinline__ void write_state(__bf16* S, int lrow, int ncol, int scol0,
                                            const float* a, const float* b) {
#pragma unroll
  for (int j = 0; j < 4; ++j) {
    int r = lrow + j;
    __bf16 h0 = (__bf16)a[j];
    lds_put(S, 512, r, scol0 + ncol, h0);
    lds_put(S, 512, r, 256 + scol0 + ncol, (__bf16)(a[j] - (float)h0));
    __bf16 h1 = (__bf16)b[j];
    lds_put(S, 512, r, scol0 + 16 + ncol, h1);
    lds_put(S, 512, r, 256 + scol0 + 16 + ncol, (__bf16)(b[j] - (float)h1));
  }
}

// Stage h (hi/lo) into A0 cols 256..511 (hi) / 512..767 (lo).
__device__ __forceinline__ void stage_h(__bf16* A0, int lrow, int ncol, int scol0,
                                        const float* a, const float* b) {
#pragma unroll
  for (int j = 0; j < 4; ++j) {
    int r = lrow + j;
    __bf16 h0 = (__bf16)a[j];
    lds_put(A0, 768, r, 256 + scol0 + ncol, h0);
    lds_put(A0, 768, r, 512 + scol0 + ncol, (__bf16)(a[j] - (float)h0));
    __bf16 h1 = (__bf16)b[j];
    lds_put(A0, 768, r, 256 + scol0 + 16 + ncol, h1);
    lds_put(A0, 768, r, 512 + scol0 + 16 + ncol, (__bf16)(b[j] - (float)h1));
  }
}

// Genotype GEMM: acc[4] tiles at n-offsets {s, s+16, 256+s, 256+s+16},
// A = [s_hi | s_lo] in a [16][512] slot (K=256 weights, hi+lo share B-frags).
__device__ __forceinline__ void gemm_step(const __bf16* Sp, const __bf16* Wt /*[512][256]*/,
                                          int scol0, int lane, f32x4* acc) {
  const int arow = lane & 15, kg = (lane >> 4) * 8, ncol = lane & 15;
  const __bf16* w0 = Wt + (scol0 + ncol) * 256 + kg;
  const __bf16* w1 = Wt + (scol0 + 16 + ncol) * 256 + kg;
  const __bf16* w2 = Wt + (256 + scol0 + ncol) * 256 + kg;
  const __bf16* w3 = Wt + (256 + scol0 + 16 + ncol) * 256 + kg;
#pragma unroll
  for (int kb = 0; kb < 8; ++kb) {
    bf16x8 b0 = *(const bf16x8*)(w0 + kb * 32);
    bf16x8 b1 = *(const bf16x8*)(w1 + kb * 32);
    bf16x8 b2 = *(const bf16x8*)(w2 + kb * 32);
    bf16x8 b3 = *(const bf16x8*)(w3 + kb * 32);
    bf16x8 ah = lds_frag(Sp, 512, arow, kb * 32 + kg);
    bf16x8 al = lds_frag(Sp, 512, arow, 256 + kb * 32 + kg);
    acc[0] = mfma16(ah, b0, acc[0]);
    acc[1] = mfma16(ah, b1, acc[1]);
    acc[2] = mfma16(ah, b2, acc[2]);
    acc[3] = mfma16(ah, b3, acc[3]);
    acc[0] = mfma16(al, b0, acc[0]);
    acc[1] = mfma16(al, b1, acc[1]);
    acc[2] = mfma16(al, b2, acc[2]);
    acc[3] = mfma16(al, b3, acc[3]);
  }
}

// ch0 GEMM: A0 = [x(256) | h_hi(256) | h_lo(256)], W0t = [512 n][512 k].
// kb 0..7 = x part, kb 8..15 = h part (h_lo reuses the same B-frags).
__device__ __forceinline__ void gemm_ch0(const __bf16* A0, const __bf16* W0t,
                                         int scol0, int lane, f32x4* acc) {
  const int arow = lane & 15, kg = (lane >> 4) * 8, ncol = lane & 15;
  const __bf16* w0 = W0t + (scol0 + ncol) * 512 + kg;
  const __bf16* w1 = W0t + (scol0 + 16 + ncol) * 512 + kg;
  const __bf16* w2 = W0t + (256 + scol0 + ncol) * 512 + kg;
  const __bf16* w3 = W0t + (256 + scol0 + 16 + ncol) * 512 + kg;
#pragma unroll
  for (int kb = 0; kb < 16; ++kb) {
    bf16x8 b0 = *(const bf16x8*)(w0 + kb * 32);
    bf16x8 b1 = *(const bf16x8*)(w1 + kb * 32);
    bf16x8 b2 = *(const bf16x8*)(w2 + kb * 32);
    bf16x8 b3 = *(const bf16x8*)(w3 + kb * 32);
    bf16x8 a = lds_frag(A0, 768, arow, kb * 32 + kg);
    acc[0] = mfma16(a, b0, acc[0]);
    acc[1] = mfma16(a, b1, acc[1]);
    acc[2] = mfma16(a, b2, acc[2]);
    acc[3] = mfma16(a, b3, acc[3]);
    if (kb >= 8) {
      bf16x8 al = lds_frag(A0, 768, arow, 256 + kb * 32 + kg);
      acc[0] = mfma16(al, b0, acc[0]);
      acc[1] = mfma16(al, b1, acc[1]);
      acc[2] = mfma16(al, b2, acc[2]);
      acc[3] = mfma16(al, b3, acc[3]);
    }
  }
}

template <int ACT>
__device__ __forceinline__ void do_step(const __bf16* Sprev, __bf16* Sout, const __bf16* Wt,
                                        int scol0, int lane, int lrow, int ncol,
                                        const float* spa, const float* spb,
                                        float* outa, float* outb, float* ma, float* mb) {
  f32x4 acc[4];
#pragma unroll
  for (int i = 0; i < 4; ++i) acc[i] = (f32x4)(0.0f);
  gemm_step(Sprev, Wt, scol0, lane, acc);
  float na[4], nb[4];
#pragma unroll
  for (int j = 0; j < 4; ++j) {
    float c0 = fsig(acc[0][j]);
    float h0 = actf<ACT>(acc[2][j]);
    na[j] = spa[j] + c0 * (h0 - spa[j]);
    float c1 = fsig(acc[1][j]);
    float h1 = actf<ACT>(acc[3][j]);
    nb[j] = spb[j] + c1 * (h1 - spb[j]);
    ma[j] += na[j];
    mb[j] += nb[j];
  }
  if (outa) {
#pragma unroll
    for (int j = 0; j < 4; ++j) { outa[j] = na[j]; outb[j] = nb[j]; }
  }
  if (Sout) write_state(Sout, lrow, ncol, scol0, na, nb);
}

// Pre-transpose weights to bf16 [n][k] so B-fragments are contiguous 16B loads.
__global__ void prep_weights(const float* __restrict__ W0, const float* __restrict__ Ws,
                             __bf16* __restrict__ wt) {
  int gid = blockIdx.x * 256 + threadIdx.x;
  const int T0 = 512 * 512;
  if (gid < T0) {
    int n = gid >> 9, k = gid & 511;
    wt[gid] = (__bf16)W0[k * 512 + n];
  } else {
    int g = gid - T0;
    int i = g >> 17;
    int r = g & 131071;
    int n = r >> 8, k = r & 255;
    wt[gid] = (__bf16)Ws[((i << 8) + k) * 512 + n];
  }
}

__global__ __launch_bounds__(NTHREADS) void darts_cell_seq(
    const float* __restrict__ X, const float* __restrict__ Hin,
    const __bf16* __restrict__ WT0, const __bf16* __restrict__ WTs,
    float* __restrict__ out) {
  __shared__ __bf16 A0[16 * 768];        // [x | h_hi | h_lo]
  __shared__ __bf16 SL[5][16 * 512];     // s0, s1, s2, s3, s5 (each [hi|lo])

  const int tid = threadIdx.x;
  const int lane = tid & 63;
  const int wv = tid >> 6;           // 0..7, owns s-cols [wv*32, wv*32+32)
  const int scol0 = wv * 32;
  const int lrow = (lane >> 4) * 4;  // C-frag rows lrow..lrow+3
  const int ncol = lane & 15;        // C-frag col
  const int rb = blockIdx.x * ROWS;  // batch-row base of this group

  float hpa[4], hpb[4];
#pragma unroll
  for (int j = 0; j < 4; ++j) {
    hpa[j] = Hin[(rb + lrow + j) * NHID + scol0 + ncol];
    hpb[j] = Hin[(rb + lrow + j) * NHID + scol0 + 16 + ncol];
  }
  stage_h(A0, lrow, ncol, scol0, hpa, hpb);

  float s0a[4], s0b[4], s1a[4], s1b[4], s2a[4], s2b[4], s3a[4], s3b[4], s5a[4], s5b[4];

  for (int t = 0; t < TT; ++t) {
    // stage x_t (16 rows x 256 f32 -> bf16), coalesced: 32 threads/row, 8 cols each
    {
      int r = tid >> 5;
      int c = (tid & 31) * 8;
      const float* xp = X + ((size_t)t * BB + rb + r) * NINP + c;
      float4 v0 = *(const float4*)xp;
      float4 v1 = *(const float4*)(xp + 4);
      bf16x8 pk;
      pk[0] = (__bf16)v0.x; pk[1] = (__bf16)v0.y; pk[2] = (__bf16)v0.z; pk[3] = (__bf16)v0.w;
      pk[4] = (__bf16)v1.x; pk[5] = (__bf16)v1.y; pk[6] = (__bf16)v1.z; pk[7] = (__bf16)v1.w;
      *(bf16x8*)((char*)A0 + lds_byte(768, r, c)) = pk;
    }
    __syncthreads();

    {  // ch0 -> s0
      f32x4 acc[4];
#pragma unroll
      for (int i = 0; i < 4; ++i) acc[i] = (f32x4)(0.0f);
      gemm_ch0(A0, WT0, scol0, lane, acc);
#pragma unroll
      for (int j = 0; j < 4; ++j) {
        float c0 = fsig(acc[0][j]);
        float h0 = ftanh(acc[2][j]);
        s0a[j] = hpa[j] + c0 * (h0 - hpa[j]);
        float c1 = fsig(acc[1][j]);
        float h1 = ftanh(acc[3][j]);
        s0b[j] = hpb[j] + c1 * (h1 - hpb[j]);
      }
      write_state(SL[0], lrow, ncol, scol0, s0a, s0b);
    }
    __syncthreads();

    float ma[4] = {0.f, 0.f, 0.f, 0.f}, mb[4] = {0.f, 0.f, 0.f, 0.f};
    // step1: sigmoid, pred s0
    do_step<0>(SL[0], SL[1], WTs + 0 * 131072, scol0, lane, lrow, ncol, s0a, s0b, s1a, s1b, ma, mb);
    __syncthreads();
    // steps 2,3 (relu, pred s1), 4 (identity, pred s1)
    do_step<1>(SL[1], SL[2], WTs + 1 * 131072, scol0, lane, lrow, ncol, s1a, s1b, s2a, s2b, ma, mb);
    do_step<1>(SL[1], SL[3], WTs + 2 * 131072, scol0, lane, lrow, ncol, s1a, s1b, s3a, s3b, ma, mb);
    do_step<3>(SL[1], nullptr, WTs + 3 * 131072, scol0, lane, lrow, ncol, s1a, s1b, nullptr, nullptr, ma, mb);
    __syncthreads();
    // step5 (tanh, pred s2), step7 (tanh, pred s3)
    do_step<2>(SL[2], SL[4], WTs + 4 * 131072, scol0, lane, lrow, ncol, s2a, s2b, s5a, s5b, ma, mb);
    do_step<2>(SL[3], nullptr, WTs + 6 * 131072, scol0, lane, lrow, ncol, s3a, s3b, nullptr, nullptr, ma, mb);
    __syncthreads();
    // step6 (sigmoid, pred s5), step8 (relu, pred s5)
    do_step<0>(SL[4], nullptr, WTs + 5 * 131072, scol0, lane, lrow, ncol, s5a, s5b, nullptr, nullptr, ma, mb);
    do_step<1>(SL[4], nullptr, WTs + 7 * 131072, scol0, lane, lrow, ncol, s5a, s5b, nullptr, nullptr, ma, mb);

    // h = mean(states 1..8)
#pragma unroll
    for (int j = 0; j < 4; ++j) { hpa[j] = ma[j] * 0.125f; hpb[j] = mb[j] * 0.125f; }
    // store hiddens[t]
#pragma unroll
    for (int j = 0; j < 4; ++j) {
      size_t base = ((size_t)t * BB + rb + lrow + j) * NHID;
      out[base + scol0 + ncol] = hpa[j];
      out[base + scol0 + 16 + ncol] = hpb[j];
    }
    if (t == TT - 1) {
#pragma unroll
      for (int j = 0; j < 4; ++j) {
        size_t base = ((size_t)TT * BB + rb + lrow + j) * NHID;
        out[base + scol0 + ncol] = hpa[j];
        out[base + scol0 + 16 + ncol] = hpb[j];
      }
    }
    stage_h(A0, lrow, ncol, scol0, hpa, hpb);
    // no trailing barrier needed: next iteration's post-stage-x barrier orders A0 h-writes
  }
}

extern "C" void kernel_launch(void* const* d_in, const int* in_sizes, int n_in,
                              void* d_out, int out_size, void* d_ws, size_t ws_size,
                              hipStream_t stream) {
  const float* X = (const float*)d_in[0];
  const float* H = (const float*)d_in[1];
  const float* W0 = (const float*)d_in[2];
  const float* Ws = (const float*)d_in[3];
  __bf16* wt = (__bf16*)d_ws;  // WT0: 512x512, then WTs: 8x512x256 (bf16)
  float* out = (float*)d_out;

  prep_weights<<<5120, 256, 0, stream>>>(W0, Ws, wt);
  darts_cell_seq<<<NGROUP, NTHREADS, 0, stream>>>(X, H, wt, wt + 262144, out);
}